// Round 15
// baseline (472.950 us; speedup 1.0000x reference)
//
#include <hip/hip_runtime.h>
#include <hip/hip_cooperative_groups.h>

namespace cg = cooperative_groups;

#define N_NODES 100000
#define DIM 64
#define N_TILES (N_NODES / 16)   // 6250 row-tiles of 16

#define BSHIFT 7
#define BN 128                         // nodes per bucket
#define NB ((N_NODES + BN - 1) / BN)   // 782 buckets
#define BC 2048                        // bucket capacity (avg 1600, ~11 sigma)

#define NBLK 512                       // 2 blocks/CU, co-resident
#define NP 256                         // partition blocks (even)
#define NT 256                         // transform blocks (odd)
#define CHUNK_P 4928                   // >= ceil(E/NP) = 4883

using bf16x8 = __attribute__((ext_vector_type(8))) short;
using f32x4  = __attribute__((ext_vector_type(4))) float;

__device__ __forceinline__ unsigned short f2bf(float f) {
    unsigned u = __float_as_uint(f);
    unsigned r = u + 0x7FFFu + ((u >> 16) & 1u);
    return (unsigned short)(r >> 16);
}

struct SortSh {
    unsigned vals[BC];       // 8 KB
    unsigned sorted[BC];     // 8 KB
    int h[BN];
    int tmp[BN];
    int offs[BN + 1];
    int cur[BN];
};                            // ~18.4 KB

union FusedShared {
    struct {
        unsigned vals[CHUNK_P];        // 19.7 KB
        unsigned short bkt[CHUNK_P];   // 9.9 KB
        int hist[NB];
        int gb[NB];
        int loff[NB];
    } p;                               // ~39 KB
    ushort t[16 * 16 * 72];            // 36.9 KB
    SortSh g[2];                       // 36.9 KB
};

// ======================= device-side phase bodies =======================

__device__ __forceinline__ void partition_body(
        const int* __restrict__ edge_src, const int* __restrict__ edge_dst,
        int* __restrict__ gcur, unsigned* __restrict__ buckets,
        int E, int pid, int tid, FusedShared& sh) {
    const int per = (E + NP - 1) / NP;
    const int e0 = pid * per;
    int e1 = e0 + per; if (e1 > E) e1 = E;

    for (int base = e0; base < e1; base += CHUNK_P) {
        int m = e1 - base; if (m > CHUNK_P) m = CHUNK_P;

        for (int i = tid; i < NB; i += 1024) sh.p.hist[i] = 0;
        __syncthreads();

        for (int i = tid; i < m; i += 1024) {
            int d = edge_dst[base + i];
            int s = edge_src[base + i];
            int b = d >> BSHIFT;
            sh.p.vals[i] = ((unsigned)(d & (BN - 1)) << 20) | (unsigned)s;
            sh.p.bkt[i] = (unsigned short)b;
            atomicAdd(&sh.p.hist[b], 1);
        }
        __syncthreads();

        for (int b = tid; b < NB; b += 1024) {
            int c = sh.p.hist[b];
            sh.p.loff[b] = 0;
            if (c > 0) sh.p.gb[b] = atomicAdd(&gcur[b], c);
        }
        __syncthreads();

        for (int i = tid; i < m; i += 1024) {
            int b = sh.p.bkt[i];
            int pos = sh.p.gb[b] + atomicAdd(&sh.p.loff[b], 1);
            if (pos < BC) buckets[(size_t)b * BC + pos] = sh.p.vals[i];
        }
        __syncthreads();
    }
}

__device__ __forceinline__ void transform_body(
        const float* __restrict__ x, const float* __restrict__ W,
        ushort* __restrict__ y, int tb, int tid, FusedShared& sh) {
    const int lane = tid & 63;
    const int w    = tid >> 6;            // 0..15
    const int l15  = lane & 15;
    const int l4   = lane >> 4;

    if (tb == 0 && tid < 8)   // zero row at index N_NODES
        ((uint4*)(y + (size_t)N_NODES * DIM))[tid] = make_uint4(0, 0, 0, 0);

    bf16x8 bfrag[4][2];
#pragma unroll
    for (int ct = 0; ct < 4; ++ct)
#pragma unroll
        for (int kt = 0; kt < 2; ++kt)
#pragma unroll
            for (int j = 0; j < 8; ++j) {
                int k = kt * 32 + l4 * 8 + j;
                int c = ct * 16 + l15;
                bfrag[ct][kt][j] = (short)f2bf(W[k * DIM + c]);
            }

    ushort* myl = sh.t + w * (16 * 72);
    const int gw = tb * 16 + w;
    const int nw = NT * 16;               // 4096 waves

    for (int rt = gw; rt < N_TILES; rt += nw) {
        const float* xt = x + (size_t)rt * 16 * DIM;

        f32x4 zero = {0.f, 0.f, 0.f, 0.f};
        f32x4 acc0 = zero, acc1 = zero, acc2 = zero, acc3 = zero;
#pragma unroll
        for (int kt = 0; kt < 2; ++kt) {
            const float* ap = xt + (size_t)l15 * DIM + kt * 32 + l4 * 8;
            float4 p0 = *(const float4*)(ap);
            float4 p1 = *(const float4*)(ap + 4);
            bf16x8 afrag;
            afrag[0] = (short)f2bf(p0.x); afrag[1] = (short)f2bf(p0.y);
            afrag[2] = (short)f2bf(p0.z); afrag[3] = (short)f2bf(p0.w);
            afrag[4] = (short)f2bf(p1.x); afrag[5] = (short)f2bf(p1.y);
            afrag[6] = (short)f2bf(p1.z); afrag[7] = (short)f2bf(p1.w);
            acc0 = __builtin_amdgcn_mfma_f32_16x16x32_bf16(afrag, bfrag[0][kt], acc0, 0, 0, 0);
            acc1 = __builtin_amdgcn_mfma_f32_16x16x32_bf16(afrag, bfrag[1][kt], acc1, 0, 0, 0);
            acc2 = __builtin_amdgcn_mfma_f32_16x16x32_bf16(afrag, bfrag[2][kt], acc2, 0, 0, 0);
            acc3 = __builtin_amdgcn_mfma_f32_16x16x32_bf16(afrag, bfrag[3][kt], acc3, 0, 0, 0);
        }

#pragma unroll
        for (int r = 0; r < 4; ++r) {
            int m = l4 * 4 + r;
            myl[m * 72 +  0 + l15] = f2bf(acc0[r]);
            myl[m * 72 + 16 + l15] = f2bf(acc1[r]);
            myl[m * 72 + 32 + l15] = f2bf(acc2[r]);
            myl[m * 72 + 48 + l15] = f2bf(acc3[r]);
        }
        int rr = lane >> 2, q = lane & 3;
        const uint4* src = (const uint4*)(myl + rr * 72 + q * 16);
        uint4 d0 = src[0];
        uint4 d1 = src[1];
        ushort* dst = y + ((size_t)(rt * 16 + rr)) * DIM + q * 16;
        *(uint4*)(dst)     = d0;
        *(uint4*)(dst + 8) = d1;
    }
    __syncthreads();
}

// one bucket per "half" of nthr threads; S = that half's shared section
__device__ __forceinline__ void sort_gather_body(
        const ushort* __restrict__ y, const int* __restrict__ gcur,
        const unsigned* __restrict__ buckets, const float* __restrict__ bias,
        float* __restrict__ out, int b, bool valid, int th, int nthr,
        SortSh& S) {
    int cnt = 0;
    if (valid) { cnt = gcur[b]; if (cnt > BC) cnt = BC; }

    for (int i = th; i < BN; i += nthr) S.h[i] = 0;
    __syncthreads();

    const unsigned* __restrict__ bk = buckets + (size_t)b * BC;
    for (int i = th; i < cnt; i += nthr) {
        unsigned v = bk[i];
        S.vals[i] = v;
        atomicAdd(&S.h[v >> 20], 1);
    }
    __syncthreads();

    if (th < BN) S.tmp[th] = S.h[th];
    __syncthreads();
    for (int o = 1; o < BN; o <<= 1) {
        int t = 0;
        if (th < BN && th >= o) t = S.tmp[th - o];
        __syncthreads();
        if (th < BN) S.tmp[th] += t;
        __syncthreads();
    }
    if (th < BN) {
        int e = S.tmp[th] - S.h[th];
        S.offs[th] = e;
        S.cur[th] = e;
    }
    if (th == 0) S.offs[BN] = cnt;
    __syncthreads();

    for (int i = th; i < cnt; i += nthr) {
        unsigned v = S.vals[i];
        int pos = atomicAdd(&S.cur[v >> 20], 1);
        S.sorted[pos] = v & 0xFFFFFu;
    }
    __syncthreads();

    const int grp = th >> 4;
    const int f   = th & 15;
    const int ngrp = nthr >> 4;
    const uint2* __restrict__ y2 = (const uint2*)y;
    float4 bb = ((const float4*)bias)[f];

    if (valid) {
        const int node0 = b * BN;
        for (int r = grp; r < BN; r += ngrp) {
            int nd = node0 + r;
            if (nd >= N_NODES) break;
            int s0i = S.offs[r], e0i = S.offs[r + 1];
            float a0 = 0.f, a1 = 0.f, a2 = 0.f, a3 = 0.f;
            for (int i = s0i; i < e0i; i += 8) {
                int idx[8];
#pragma unroll
                for (int k = 0; k < 8; ++k)
                    idx[k] = (i + k < e0i) ? (int)S.sorted[i + k] : N_NODES;
#pragma unroll
                for (int k = 0; k < 8; ++k) {
                    uint2 v = y2[(size_t)idx[k] * 16 + f];
                    a0 += __uint_as_float(v.x << 16);
                    a1 += __uint_as_float(v.x & 0xffff0000u);
                    a2 += __uint_as_float(v.y << 16);
                    a3 += __uint_as_float(v.y & 0xffff0000u);
                }
            }
            float4 o;
            o.x = a0 + bb.x; o.y = a1 + bb.y;
            o.z = a2 + bb.z; o.w = a3 + bb.w;
            *(float4*)(out + (size_t)nd * DIM + f * 4) = o;
        }
    }
}

// ======================= cooperative fused kernel =======================
// 512 blocks x 1024 threads = 2 blocks/CU -> 32 waves/CU = 8 waves/SIMD.
// __launch_bounds__ 2nd arg is waves per SIMD (EU): must be 8, not 2
// (R13 bug: arg=2 let VGPR>64, co-residency failed, launch no-op'd).
__global__ __launch_bounds__(1024, 8)
void fused_kernel(const float* __restrict__ x,
                  const float* __restrict__ W,
                  const int* __restrict__ edge_src,
                  const int* __restrict__ edge_dst,
                  int* __restrict__ gcur,
                  unsigned* __restrict__ buckets,
                  ushort* __restrict__ y,
                  const float* __restrict__ bias,
                  float* __restrict__ out, int E) {
    __shared__ FusedShared sh;
    cg::grid_group grid = cg::this_grid();
    const int tid = threadIdx.x;

    // phase 0: zero gcur (y zero-row done by transform block 0)
    {
        int gtid = blockIdx.x * 1024 + tid;
        if (gtid < NB) gcur[gtid] = 0;
    }
    __threadfence();
    grid.sync();

    // phase 1: partition (even blocks) / transform (odd blocks)
    if ((blockIdx.x & 1) == 0)
        partition_body(edge_src, edge_dst, gcur, buckets, E,
                       blockIdx.x >> 1, tid, sh);
    else
        transform_body(x, W, y, blockIdx.x >> 1, tid, sh);
    __threadfence();
    grid.sync();

    // phase 2: 1024 half-blocks cover 782 buckets in one pass
    {
        const int half = tid >> 9;                  // 0/1
        const int th   = tid & 511;
        const int b    = blockIdx.x + half * NBLK;  // 0..1023
        sort_gather_body(y, gcur, buckets, bias, out,
                         b, b < NB, th, 512, sh.g[half]);
    }
}

// ======================= fallback (R12) kernels =========================

__global__ __launch_bounds__(1024, 2)
void prep_kernel(const float* __restrict__ x,
                 const float* __restrict__ W,
                 const int* __restrict__ edge_src,
                 const int* __restrict__ edge_dst,
                 int* __restrict__ gcur,
                 unsigned* __restrict__ buckets,
                 ushort* __restrict__ y, int E) {
    __shared__ FusedShared sh;
    const int tid = threadIdx.x;
    if ((blockIdx.x & 1) == 0)
        partition_body(edge_src, edge_dst, gcur, buckets, E,
                       blockIdx.x >> 1, tid, sh);
    else
        transform_body(x, W, y, blockIdx.x >> 1, tid, sh);
}

__global__ void sort_gather_kernel(const ushort* __restrict__ y,
                                   const int* __restrict__ gcur,
                                   const unsigned* __restrict__ buckets,
                                   const float* __restrict__ bias,
                                   float* __restrict__ out) {
    __shared__ SortSh S;
    sort_gather_body(y, gcur, buckets, bias, out,
                     blockIdx.x, true, threadIdx.x, 256, S);
}

// ======================= launch =========================================

extern "C" void kernel_launch(void* const* d_in, const int* in_sizes, int n_in,
                              void* d_out, int out_size, void* d_ws, size_t ws_size,
                              hipStream_t stream) {
    const float* x        = (const float*)d_in[0];
    const int*   edge_src = (const int*)d_in[1];
    const int*   edge_dst = (const int*)d_in[2];
    const float* W        = (const float*)d_in[3];
    const float* b        = (const float*)d_in[4];
    float* out = (float*)d_out;

    int E = in_sizes[1];

    // ws layout: y[(N+1)*64] bf16 (12.8 MB) | gcur[NB] | buckets[NB*BC] (6.4 MB)
    ushort*   y       = (ushort*)d_ws;
    int*      gcur    = (int*)(y + (size_t)(N_NODES + 1) * DIM);
    unsigned* buckets = (unsigned*)(gcur + NB);

    void* args[] = { (void*)&x, (void*)&W, (void*)&edge_src, (void*)&edge_dst,
                     (void*)&gcur, (void*)&buckets, (void*)&y, (void*)&b,
                     (void*)&out, (void*)&E };
    hipError_t err = hipLaunchCooperativeKernel((const void*)fused_kernel,
                                                dim3(NBLK), dim3(1024), args,
                                                0, stream);
    if (err != hipSuccess) {
        // fallback: proven 3-dispatch R12 path
        hipMemsetAsync(gcur, 0, NB * sizeof(int), stream);
        prep_kernel<<<NP + NT, 1024, 0, stream>>>(x, W, edge_src, edge_dst,
                                                  gcur, buckets, y, E);
        sort_gather_kernel<<<NB, 256, 0, stream>>>(y, gcur, buckets, b, out);
    }
}

// Round 16
// 64.540 us; speedup vs baseline: 7.3280x; 7.3280x over previous
//
#include <hip/hip_runtime.h>

#define N_NODES 100000
#define DIM 64
#define N_TILES (N_NODES / 16)   // 6250 row-tiles of 16

#define BSHIFT 7
#define BN 128                         // nodes per bucket
#define NB ((N_NODES + BN - 1) / BN)   // 782 buckets
#define BC 2048                        // bucket capacity (avg 1600, ~11 sigma)

#define NP 352                         // partition blocks (0..NP)
#define NT 160                         // transform blocks (NP..NP+NT)
#define CHUNK_P 4928                   // >= per = ceil(E/NP) rounded to x4

using bf16x8 = __attribute__((ext_vector_type(8))) short;
using f32x4  = __attribute__((ext_vector_type(4))) float;

__device__ __forceinline__ unsigned short f2bf(float f) {
    unsigned u = __float_as_uint(f);
    unsigned r = u + 0x7FFFu + ((u >> 16) & 1u);
    return (unsigned short)(r >> 16);
}

union PrepShared {
    struct {
        unsigned vals[CHUNK_P];        // 19.7 KB packed entries
        unsigned short bkt[CHUNK_P];   // 9.9 KB bucket ids
        int hist[NB];                  // 3.1 KB each
        int gb[NB];
        int loff[NB];
    } p;                               // ~39 KB
    ushort t[16 * 16 * 72];            // 36.9 KB
};

// ---- fused pass 1: blocks [0,NP) partition, [NP,NP+NT) transform -------
__global__ __launch_bounds__(1024, 2)
void prep_kernel(const float* __restrict__ x,
                 const float* __restrict__ W,
                 const int* __restrict__ edge_src,
                 const int* __restrict__ edge_dst,
                 int* __restrict__ gcur,
                 unsigned* __restrict__ buckets,
                 ushort* __restrict__ y, int E) {
    __shared__ PrepShared sh;
    const int tid = threadIdx.x;

    if (blockIdx.x < NP) {
        // ---------- partition: int4-vectorized loads --------------------
        const int pid = blockIdx.x;
        const int per = (((E + NP - 1) / NP) + 3) & ~3;   // x4 aligned
        const int e0 = pid * per;
        int e1 = e0 + per; if (e1 > E) e1 = E;
        if (e0 >= E) return;

        for (int base = e0; base < e1; base += CHUNK_P) {
            int m = e1 - base; if (m > CHUNK_P) m = CHUNK_P;

            for (int i = tid; i < NB; i += 1024) sh.p.hist[i] = 0;
            __syncthreads();

            // load + pack + histogram (4 edges/thread/iter)
            {
                const int G = m >> 2;
                const int4* __restrict__ d4p = (const int4*)(edge_dst + base);
                const int4* __restrict__ s4p = (const int4*)(edge_src + base);
                for (int g = tid; g < G; g += 1024) {
                    int4 d = d4p[g];
                    int4 s = s4p[g];
                    uint4 v;
                    v.x = ((unsigned)(d.x & (BN - 1)) << 20) | (unsigned)s.x;
                    v.y = ((unsigned)(d.y & (BN - 1)) << 20) | (unsigned)s.y;
                    v.z = ((unsigned)(d.z & (BN - 1)) << 20) | (unsigned)s.z;
                    v.w = ((unsigned)(d.w & (BN - 1)) << 20) | (unsigned)s.w;
                    *(uint4*)(sh.p.vals + (g << 2)) = v;
                    ushort4 bk;
                    bk.x = (unsigned short)(d.x >> BSHIFT);
                    bk.y = (unsigned short)(d.y >> BSHIFT);
                    bk.z = (unsigned short)(d.z >> BSHIFT);
                    bk.w = (unsigned short)(d.w >> BSHIFT);
                    *(ushort4*)(sh.p.bkt + (g << 2)) = bk;
                    atomicAdd(&sh.p.hist[bk.x], 1);
                    atomicAdd(&sh.p.hist[bk.y], 1);
                    atomicAdd(&sh.p.hist[bk.z], 1);
                    atomicAdd(&sh.p.hist[bk.w], 1);
                }
                // tail (m % 4): only last chunk of last active block
                for (int i = (G << 2) + tid; i < m; i += 1024) {
                    int d = edge_dst[base + i];
                    int s = edge_src[base + i];
                    int b = d >> BSHIFT;
                    sh.p.vals[i] = ((unsigned)(d & (BN - 1)) << 20) | (unsigned)s;
                    sh.p.bkt[i] = (unsigned short)b;
                    atomicAdd(&sh.p.hist[b], 1);
                }
            }
            __syncthreads();

            for (int b = tid; b < NB; b += 1024) {
                int c = sh.p.hist[b];
                sh.p.loff[b] = 0;
                if (c > 0) sh.p.gb[b] = atomicAdd(&gcur[b], c);
            }
            __syncthreads();

            for (int i = tid; i < m; i += 1024) {
                int b = sh.p.bkt[i];
                int pos = sh.p.gb[b] + atomicAdd(&sh.p.loff[b], 1);
                if (pos < BC) buckets[(size_t)b * BC + pos] = sh.p.vals[i];
            }
            __syncthreads();
        }
    } else {
        // ---------- transform: y = bf16(x @ W), MFMA, 16 waves ----------
        const int lane = tid & 63;
        const int w    = tid >> 6;            // 0..15
        const int l15  = lane & 15;
        const int l4   = lane >> 4;
        const int tb   = blockIdx.x - NP;

        if (tb == 0 && tid < 8)   // zero row at index N_NODES
            ((uint4*)(y + (size_t)N_NODES * DIM))[tid] = make_uint4(0, 0, 0, 0);

        bf16x8 bfrag[4][2];
#pragma unroll
        for (int ct = 0; ct < 4; ++ct)
#pragma unroll
            for (int kt = 0; kt < 2; ++kt)
#pragma unroll
                for (int j = 0; j < 8; ++j) {
                    int k = kt * 32 + l4 * 8 + j;
                    int c = ct * 16 + l15;
                    bfrag[ct][kt][j] = (short)f2bf(W[k * DIM + c]);
                }

        ushort* myl = sh.t + w * (16 * 72);
        const int gw = tb * 16 + w;
        const int nw = NT * 16;               // 2560 waves

        for (int rt = gw; rt < N_TILES; rt += nw) {
            const float* xt = x + (size_t)rt * 16 * DIM;

            f32x4 zero = {0.f, 0.f, 0.f, 0.f};
            f32x4 acc0 = zero, acc1 = zero, acc2 = zero, acc3 = zero;
#pragma unroll
            for (int kt = 0; kt < 2; ++kt) {
                const float* ap = xt + (size_t)l15 * DIM + kt * 32 + l4 * 8;
                float4 p0 = *(const float4*)(ap);
                float4 p1 = *(const float4*)(ap + 4);
                bf16x8 afrag;
                afrag[0] = (short)f2bf(p0.x); afrag[1] = (short)f2bf(p0.y);
                afrag[2] = (short)f2bf(p0.z); afrag[3] = (short)f2bf(p0.w);
                afrag[4] = (short)f2bf(p1.x); afrag[5] = (short)f2bf(p1.y);
                afrag[6] = (short)f2bf(p1.z); afrag[7] = (short)f2bf(p1.w);
                acc0 = __builtin_amdgcn_mfma_f32_16x16x32_bf16(afrag, bfrag[0][kt], acc0, 0, 0, 0);
                acc1 = __builtin_amdgcn_mfma_f32_16x16x32_bf16(afrag, bfrag[1][kt], acc1, 0, 0, 0);
                acc2 = __builtin_amdgcn_mfma_f32_16x16x32_bf16(afrag, bfrag[2][kt], acc2, 0, 0, 0);
                acc3 = __builtin_amdgcn_mfma_f32_16x16x32_bf16(afrag, bfrag[3][kt], acc3, 0, 0, 0);
            }

#pragma unroll
            for (int r = 0; r < 4; ++r) {
                int m = l4 * 4 + r;
                myl[m * 72 +  0 + l15] = f2bf(acc0[r]);
                myl[m * 72 + 16 + l15] = f2bf(acc1[r]);
                myl[m * 72 + 32 + l15] = f2bf(acc2[r]);
                myl[m * 72 + 48 + l15] = f2bf(acc3[r]);
            }
            int rr = lane >> 2, q = lane & 3;
            const uint4* src = (const uint4*)(myl + rr * 72 + q * 16);
            uint4 d0 = src[0];
            uint4 d1 = src[1];
            ushort* dst = y + ((size_t)(rt * 16 + rr)) * DIM + q * 16;
            *(uint4*)(dst)     = d0;
            *(uint4*)(dst + 8) = d1;
        }
    }
}

// ---- pass 2: per-bucket counting sort + register-accumulated gather ----
__global__ void sort_gather_kernel(const ushort* __restrict__ y,
                                   const int* __restrict__ gcur,
                                   const unsigned* __restrict__ buckets,
                                   const float* __restrict__ bias,
                                   float* __restrict__ out) {
    __shared__ unsigned vals[BC];      // 8 KB staged entries
    __shared__ unsigned sorted[BC];    // 8 KB sorted src indices
    __shared__ int h[BN];
    __shared__ int tmp[BN];
    __shared__ int offs[BN + 1];
    __shared__ int cur[BN];

    const int tid = threadIdx.x;
    const int b = blockIdx.x;

    int cnt = gcur[b];
    if (cnt > BC) cnt = BC;

    for (int i = tid; i < BN; i += blockDim.x) h[i] = 0;
    __syncthreads();

    const unsigned* __restrict__ bk = buckets + (size_t)b * BC;
    for (int i = tid; i < cnt; i += blockDim.x) {
        unsigned v = bk[i];
        vals[i] = v;
        atomicAdd(&h[v >> 20], 1);
    }
    __syncthreads();

    if (tid < BN) tmp[tid] = h[tid];
    __syncthreads();
    for (int o = 1; o < BN; o <<= 1) {
        int t = 0;
        if (tid < BN && tid >= o) t = tmp[tid - o];
        __syncthreads();
        if (tid < BN) tmp[tid] += t;
        __syncthreads();
    }
    if (tid < BN) {
        int e = tmp[tid] - h[tid];       // exclusive
        offs[tid] = e;
        cur[tid] = e;
    }
    if (tid == 0) offs[BN] = cnt;
    __syncthreads();

    for (int i = tid; i < cnt; i += blockDim.x) {
        unsigned v = vals[i];
        int dl = v >> 20;
        int pos = atomicAdd(&cur[dl], 1);
        sorted[pos] = v & 0xFFFFFu;
    }
    __syncthreads();

    const int grp = tid >> 4;        // 16 groups of 16 lanes
    const int f = tid & 15;
    const uint2* __restrict__ y2 = (const uint2*)y;
    const int node0 = b * BN;
    float4 bb = ((const float4*)bias)[f];

    for (int r = grp; r < BN; r += 16) {
        int nd = node0 + r;
        if (nd >= N_NODES) break;
        int s0i = offs[r], e0i = offs[r + 1];
        float a0 = 0.f, a1 = 0.f, a2 = 0.f, a3 = 0.f;
        for (int i = s0i; i < e0i; i += 8) {
            int idx[8];
#pragma unroll
            for (int k = 0; k < 8; ++k)
                idx[k] = (i + k < e0i) ? (int)sorted[i + k] : N_NODES;
#pragma unroll
            for (int k = 0; k < 8; ++k) {
                uint2 v = y2[(size_t)idx[k] * 16 + f];
                a0 += __uint_as_float(v.x << 16);
                a1 += __uint_as_float(v.x & 0xffff0000u);
                a2 += __uint_as_float(v.y << 16);
                a3 += __uint_as_float(v.y & 0xffff0000u);
            }
        }
        float4 o;
        o.x = a0 + bb.x; o.y = a1 + bb.y; o.z = a2 + bb.z; o.w = a3 + bb.w;
        *(float4*)(out + (size_t)nd * DIM + f * 4) = o;
    }
}

// ---- Launch ------------------------------------------------------------

extern "C" void kernel_launch(void* const* d_in, const int* in_sizes, int n_in,
                              void* d_out, int out_size, void* d_ws, size_t ws_size,
                              hipStream_t stream) {
    const float* x        = (const float*)d_in[0];
    const int*   edge_src = (const int*)d_in[1];
    const int*   edge_dst = (const int*)d_in[2];
    const float* W        = (const float*)d_in[3];
    const float* b        = (const float*)d_in[4];
    float* out = (float*)d_out;

    const int E = in_sizes[1];

    // ws layout: y[(N+1)*64] bf16 (12.8 MB) | gcur[NB] | buckets[NB*BC] (6.4 MB)
    ushort*   y       = (ushort*)d_ws;
    int*      gcur    = (int*)(y + (size_t)(N_NODES + 1) * DIM);
    unsigned* buckets = (unsigned*)(gcur + NB);

    hipMemsetAsync(gcur, 0, NB * sizeof(int), stream);

    prep_kernel<<<NP + NT, 1024, 0, stream>>>(x, W, edge_src, edge_dst,
                                              gcur, buckets, y, E);
    sort_gather_kernel<<<NB, 256, 0, stream>>>(y, gcur, buckets, b, out);
}

// Round 17
// 60.028 us; speedup vs baseline: 7.8789x; 1.0752x over previous
//
#include <hip/hip_runtime.h>

#define N_NODES 100000
#define DIM 64
#define N_TILES (N_NODES / 16)   // 6250 row-tiles of 16

#define BSHIFT 7
#define BN 128                         // nodes per bucket
#define NB ((N_NODES + BN - 1) / BN)   // 782 buckets
#define BC 2048                        // bucket capacity (mean 1598, ~11 sigma)

#define NP 256                         // partition blocks (even)
#define NT 256                         // transform blocks (odd)
#define CHUNK_P 4928                   // >= per = ceil(E/NP) rounded to x4

using bf16x8 = __attribute__((ext_vector_type(8))) short;
using f32x4  = __attribute__((ext_vector_type(4))) float;

__device__ __forceinline__ unsigned short f2bf(float f) {
    unsigned u = __float_as_uint(f);
    unsigned r = u + 0x7FFFu + ((u >> 16) & 1u);
    return (unsigned short)(r >> 16);
}

union PrepShared {
    struct {
        unsigned vals[CHUNK_P];        // 19.7 KB packed entries
        unsigned srt[CHUNK_P];         // 19.7 KB bucket-sorted entries
        unsigned short bkt[CHUNK_P];   // 9.9 KB bucket ids
        int hist[NB];
        int offs[NB];
        int cur[NB];
    } p;                               // ~58.7 KB
    ushort t[16 * 16 * 72];            // 36.9 KB
};                                      // 2 blocks/CU: 117 KB <= 160 KB

// ---- pass 1: even blocks = partition (block-local counting sort,
// ----         dense sequential writeout + per-block offset table),
// ----         odd blocks = transform (MFMA) ----------------------------
__global__ __launch_bounds__(1024, 2)
void prep_kernel(const float* __restrict__ x,
                 const float* __restrict__ W,
                 const int* __restrict__ edge_src,
                 const int* __restrict__ edge_dst,
                 int* __restrict__ blk_offs,      // [NP][NB+1]
                 unsigned* __restrict__ bsorted,  // [NP][per4]
                 ushort* __restrict__ y, int E, int per4) {
    __shared__ PrepShared sh;
    const int tid = threadIdx.x;

    if ((blockIdx.x & 1) == 0) {
        // ---------- partition -------------------------------------------
        const int pid = blockIdx.x >> 1;
        const int e0 = pid * per4;
        int m = E - e0;
        if (m < 0) m = 0;
        if (m > per4) m = per4;

        for (int i = tid; i < NB; i += 1024) sh.p.hist[i] = 0;
        __syncthreads();

        // load + pack + histogram (int4: 4 edges/thread/iter)
        {
            const int G = m >> 2;
            const int4* __restrict__ d4p = (const int4*)(edge_dst + e0);
            const int4* __restrict__ s4p = (const int4*)(edge_src + e0);
            for (int g = tid; g < G; g += 1024) {
                int4 d = d4p[g];
                int4 s = s4p[g];
                uint4 v;
                v.x = ((unsigned)(d.x & (BN - 1)) << 20) | (unsigned)s.x;
                v.y = ((unsigned)(d.y & (BN - 1)) << 20) | (unsigned)s.y;
                v.z = ((unsigned)(d.z & (BN - 1)) << 20) | (unsigned)s.z;
                v.w = ((unsigned)(d.w & (BN - 1)) << 20) | (unsigned)s.w;
                *(uint4*)(sh.p.vals + (g << 2)) = v;
                ushort4 bk;
                bk.x = (unsigned short)(d.x >> BSHIFT);
                bk.y = (unsigned short)(d.y >> BSHIFT);
                bk.z = (unsigned short)(d.z >> BSHIFT);
                bk.w = (unsigned short)(d.w >> BSHIFT);
                *(ushort4*)(sh.p.bkt + (g << 2)) = bk;
                atomicAdd(&sh.p.hist[bk.x], 1);
                atomicAdd(&sh.p.hist[bk.y], 1);
                atomicAdd(&sh.p.hist[bk.z], 1);
                atomicAdd(&sh.p.hist[bk.w], 1);
            }
            for (int i = (G << 2) + tid; i < m; i += 1024) {
                int d = edge_dst[e0 + i];
                int s = edge_src[e0 + i];
                int b = d >> BSHIFT;
                sh.p.vals[i] = ((unsigned)(d & (BN - 1)) << 20) | (unsigned)s;
                sh.p.bkt[i] = (unsigned short)b;
                atomicAdd(&sh.p.hist[b], 1);
            }
        }
        __syncthreads();

        // exclusive scan of hist over NB (Hillis-Steele, 10 rounds)
        if (tid < NB) sh.p.offs[tid] = sh.p.hist[tid];
        __syncthreads();
        for (int o = 1; o < NB; o <<= 1) {
            int t = 0;
            if (tid < NB && tid >= o) t = sh.p.offs[tid - o];
            __syncthreads();
            if (tid < NB) sh.p.offs[tid] += t;
            __syncthreads();
        }
        if (tid < NB) {
            int e = sh.p.offs[tid] - sh.p.hist[tid];   // exclusive
            sh.p.offs[tid] = e;
            sh.p.cur[tid] = e;
            blk_offs[pid * (NB + 1) + tid] = e;        // dense table write
        }
        if (tid == 0) blk_offs[pid * (NB + 1) + NB] = m;
        __syncthreads();

        // LDS counting-sort scatter (bucket-grouped)
        for (int i = tid; i < m; i += 1024) {
            int b = sh.p.bkt[i];
            int pos = atomicAdd(&sh.p.cur[b], 1);
            sh.p.srt[pos] = sh.p.vals[i];
        }
        __syncthreads();

        // fully coalesced sequential writeout of the sorted chunk
        unsigned* __restrict__ dst = bsorted + (size_t)pid * per4;
        for (int i = tid; i < m; i += 1024) dst[i] = sh.p.srt[i];
    } else {
        // ---------- transform: y = bf16(x @ W), MFMA, 16 waves ----------
        const int lane = tid & 63;
        const int w    = tid >> 6;            // 0..15
        const int l15  = lane & 15;
        const int l4   = lane >> 4;
        const int tb   = blockIdx.x >> 1;

        if (tb == 0 && tid < 8)   // zero row at index N_NODES
            ((uint4*)(y + (size_t)N_NODES * DIM))[tid] = make_uint4(0, 0, 0, 0);

        bf16x8 bfrag[4][2];
#pragma unroll
        for (int ct = 0; ct < 4; ++ct)
#pragma unroll
            for (int kt = 0; kt < 2; ++kt)
#pragma unroll
                for (int j = 0; j < 8; ++j) {
                    int k = kt * 32 + l4 * 8 + j;
                    int c = ct * 16 + l15;
                    bfrag[ct][kt][j] = (short)f2bf(W[k * DIM + c]);
                }

        ushort* myl = sh.t + w * (16 * 72);
        const int gw = tb * 16 + w;
        const int nw = NT * 16;

        for (int rt = gw; rt < N_TILES; rt += nw) {
            const float* xt = x + (size_t)rt * 16 * DIM;

            f32x4 zero = {0.f, 0.f, 0.f, 0.f};
            f32x4 acc0 = zero, acc1 = zero, acc2 = zero, acc3 = zero;
#pragma unroll
            for (int kt = 0; kt < 2; ++kt) {
                const float* ap = xt + (size_t)l15 * DIM + kt * 32 + l4 * 8;
                float4 p0 = *(const float4*)(ap);
                float4 p1 = *(const float4*)(ap + 4);
                bf16x8 afrag;
                afrag[0] = (short)f2bf(p0.x); afrag[1] = (short)f2bf(p0.y);
                afrag[2] = (short)f2bf(p0.z); afrag[3] = (short)f2bf(p0.w);
                afrag[4] = (short)f2bf(p1.x); afrag[5] = (short)f2bf(p1.y);
                afrag[6] = (short)f2bf(p1.z); afrag[7] = (short)f2bf(p1.w);
                acc0 = __builtin_amdgcn_mfma_f32_16x16x32_bf16(afrag, bfrag[0][kt], acc0, 0, 0, 0);
                acc1 = __builtin_amdgcn_mfma_f32_16x16x32_bf16(afrag, bfrag[1][kt], acc1, 0, 0, 0);
                acc2 = __builtin_amdgcn_mfma_f32_16x16x32_bf16(afrag, bfrag[2][kt], acc2, 0, 0, 0);
                acc3 = __builtin_amdgcn_mfma_f32_16x16x32_bf16(afrag, bfrag[3][kt], acc3, 0, 0, 0);
            }

#pragma unroll
            for (int r = 0; r < 4; ++r) {
                int mm = l4 * 4 + r;
                myl[mm * 72 +  0 + l15] = f2bf(acc0[r]);
                myl[mm * 72 + 16 + l15] = f2bf(acc1[r]);
                myl[mm * 72 + 32 + l15] = f2bf(acc2[r]);
                myl[mm * 72 + 48 + l15] = f2bf(acc3[r]);
            }
            int rr = lane >> 2, q = lane & 3;
            const uint4* src = (const uint4*)(myl + rr * 72 + q * 16);
            uint4 d0 = src[0];
            uint4 d1 = src[1];
            ushort* dst = y + ((size_t)(rt * 16 + rr)) * DIM + q * 16;
            *(uint4*)(dst)     = d0;
            *(uint4*)(dst + 8) = d1;
        }
    }
}

// ---- pass 2: assemble bucket from 256 runs + counting sort + gather ----
__global__ void sort_gather_kernel(const ushort* __restrict__ y,
                                   const int* __restrict__ blk_offs,
                                   const unsigned* __restrict__ bsorted,
                                   const float* __restrict__ bias,
                                   float* __restrict__ out, int per4) {
    __shared__ unsigned vals[BC];      // 8 KB assembled entries
    __shared__ unsigned sorted[BC];    // 8 KB sorted src indices
    __shared__ int lens[NP];
    __shared__ int starts[NP];
    __shared__ int h[BN];
    __shared__ int tmp[BN];
    __shared__ int offs[BN + 1];
    __shared__ int cur[BN];
    __shared__ int cnt_sh;

    const int tid = threadIdx.x;     // 256 threads == NP
    const int b = blockIdx.x;

    // stage A: per-block run table for this bucket + scan of lengths
    int lo = 0, len = 0;
    {
        const int* po = blk_offs + tid * (NB + 1);
        lo = po[b];
        len = po[b + 1] - lo;
        lens[tid] = len;
        starts[tid] = len;
    }
    __syncthreads();
    for (int o = 1; o < NP; o <<= 1) {
        int t = 0;
        if (tid >= o) t = starts[tid - o];
        __syncthreads();
        starts[tid] += t;
        __syncthreads();
    }
    if (tid == NP - 1) cnt_sh = starts[NP - 1];
    __syncthreads();
    int cnt = cnt_sh;
    if (cnt > BC) cnt = BC;

    // stage B: copy runs into vals (one run per thread, L2-resident reads)
    {
        int st = starts[tid] - len;    // exclusive prefix
        const unsigned* __restrict__ src = bsorted + (size_t)tid * per4 + lo;
        for (int j = 0; j < len; ++j) {
            int p = st + j;
            if (p < BC) vals[p] = src[j];
        }
    }

    // stage C: counting sort by local node id
    for (int i = tid; i < BN; i += 256) h[i] = 0;
    __syncthreads();
    for (int i = tid; i < cnt; i += 256) atomicAdd(&h[vals[i] >> 20], 1);
    __syncthreads();

    if (tid < BN) tmp[tid] = h[tid];
    __syncthreads();
    for (int o = 1; o < BN; o <<= 1) {
        int t = 0;
        if (tid < BN && tid >= o) t = tmp[tid - o];
        __syncthreads();
        if (tid < BN) tmp[tid] += t;
        __syncthreads();
    }
    if (tid < BN) {
        int e = tmp[tid] - h[tid];
        offs[tid] = e;
        cur[tid] = e;
    }
    if (tid == 0) offs[BN] = cnt;
    __syncthreads();

    for (int i = tid; i < cnt; i += 256) {
        unsigned v = vals[i];
        int pos = atomicAdd(&cur[v >> 20], 1);
        sorted[pos] = v & 0xFFFFFu;
    }
    __syncthreads();

    // stage D: register-accumulated gather + bias + coalesced store
    const int grp = tid >> 4;        // 16 groups of 16 lanes
    const int f = tid & 15;
    const uint2* __restrict__ y2 = (const uint2*)y;
    const int node0 = b * BN;
    float4 bb = ((const float4*)bias)[f];

    for (int r = grp; r < BN; r += 16) {
        int nd = node0 + r;
        if (nd >= N_NODES) break;
        int s0i = offs[r], e0i = offs[r + 1];
        float a0 = 0.f, a1 = 0.f, a2 = 0.f, a3 = 0.f;
        for (int i = s0i; i < e0i; i += 8) {
            int idx[8];
#pragma unroll
            for (int k = 0; k < 8; ++k)
                idx[k] = (i + k < e0i) ? (int)sorted[i + k] : N_NODES;
#pragma unroll
            for (int k = 0; k < 8; ++k) {
                uint2 v = y2[(size_t)idx[k] * 16 + f];
                a0 += __uint_as_float(v.x << 16);
                a1 += __uint_as_float(v.x & 0xffff0000u);
                a2 += __uint_as_float(v.y << 16);
                a3 += __uint_as_float(v.y & 0xffff0000u);
            }
        }
        float4 o;
        o.x = a0 + bb.x; o.y = a1 + bb.y; o.z = a2 + bb.z; o.w = a3 + bb.w;
        *(float4*)(out + (size_t)nd * DIM + f * 4) = o;
    }
}

// ---- Launch ------------------------------------------------------------

extern "C" void kernel_launch(void* const* d_in, const int* in_sizes, int n_in,
                              void* d_out, int out_size, void* d_ws, size_t ws_size,
                              hipStream_t stream) {
    const float* x        = (const float*)d_in[0];
    const int*   edge_src = (const int*)d_in[1];
    const int*   edge_dst = (const int*)d_in[2];
    const float* W        = (const float*)d_in[3];
    const float* b        = (const float*)d_in[4];
    float* out = (float*)d_out;

    const int E = in_sizes[1];
    int per4 = (((E + NP - 1) / NP) + 3) & ~3;   // 4884 for E=1.25M
    if (per4 > CHUNK_P) per4 = CHUNK_P;          // safety (not hit here)

    // ws layout: y[(N+1)*64] bf16 (12.8 MB) | bsorted[NP*CHUNK_P] (5.05 MB)
    //            | blk_offs[NP*(NB+1)] (0.80 MB)   -- no memset needed
    ushort*   y        = (ushort*)d_ws;
    unsigned* bsorted  = (unsigned*)(y + (size_t)(N_NODES + 1) * DIM);
    int*      blk_offs = (int*)(bsorted + (size_t)NP * CHUNK_P);

    prep_kernel<<<NP + NT, 1024, 0, stream>>>(x, W, edge_src, edge_dst,
                                              blk_offs, bsorted, y, E, per4);
    sort_gather_kernel<<<NB, 256, 0, stream>>>(y, blk_offs, bsorted, b, out,
                                               per4);
}

// Round 18
// 59.913 us; speedup vs baseline: 7.8940x; 1.0019x over previous
//
#include <hip/hip_runtime.h>

#define N_NODES 100000
#define DIM 64
#define N_TILES (N_NODES / 16)   // 6250 row-tiles of 16

#define BSHIFT 7
#define BN 128                         // nodes per bucket
#define NB ((N_NODES + BN - 1) / BN)   // 782 buckets
#define BC 2048                        // bucket capacity (mean 1598, ~11 sigma)

#define NP 256                         // partition blocks (even)
#define NT 256                         // transform blocks (odd)
#define CHUNK_P 4928                   // >= per = ceil(E/NP) rounded to x4

using bf16x8 = __attribute__((ext_vector_type(8))) short;
using f32x4  = __attribute__((ext_vector_type(4))) float;

__device__ __forceinline__ unsigned short f2bf(float f) {
    unsigned u = __float_as_uint(f);
    unsigned r = u + 0x7FFFu + ((u >> 16) & 1u);
    return (unsigned short)(r >> 16);
}

union PrepShared {
    struct {
        unsigned vals[CHUNK_P];        // 19.7 KB packed entries
        unsigned srt[CHUNK_P];         // 19.7 KB bucket-sorted entries
        unsigned short bkt[CHUNK_P];   // 9.9 KB bucket ids
        int hist[NB];
        int offs[NB];
        int cur[NB];
    } p;                               // ~58.7 KB
    ushort t[16 * 16 * 72];            // 36.9 KB
};                                      // 2 blocks/CU: 117 KB <= 160 KB

// ---- pass 1: even blocks = partition (block-local counting sort,
// ----         dense sequential writeout + per-block offset table),
// ----         odd blocks = transform (MFMA) ----------------------------
__global__ __launch_bounds__(1024, 2)
void prep_kernel(const float* __restrict__ x,
                 const float* __restrict__ W,
                 const int* __restrict__ edge_src,
                 const int* __restrict__ edge_dst,
                 int* __restrict__ blk_offs,      // [NP][NB+1]
                 unsigned* __restrict__ bsorted,  // [NP][per4]
                 ushort* __restrict__ y, int E, int per4) {
    __shared__ PrepShared sh;
    const int tid = threadIdx.x;

    if ((blockIdx.x & 1) == 0) {
        // ---------- partition -------------------------------------------
        const int pid = blockIdx.x >> 1;
        const int e0 = pid * per4;
        int m = E - e0;
        if (m < 0) m = 0;
        if (m > per4) m = per4;

        for (int i = tid; i < NB; i += 1024) sh.p.hist[i] = 0;
        __syncthreads();

        // load + pack + histogram (int4: 4 edges/thread/iter)
        {
            const int G = m >> 2;
            const int4* __restrict__ d4p = (const int4*)(edge_dst + e0);
            const int4* __restrict__ s4p = (const int4*)(edge_src + e0);
            for (int g = tid; g < G; g += 1024) {
                int4 d = d4p[g];
                int4 s = s4p[g];
                uint4 v;
                v.x = ((unsigned)(d.x & (BN - 1)) << 20) | (unsigned)s.x;
                v.y = ((unsigned)(d.y & (BN - 1)) << 20) | (unsigned)s.y;
                v.z = ((unsigned)(d.z & (BN - 1)) << 20) | (unsigned)s.z;
                v.w = ((unsigned)(d.w & (BN - 1)) << 20) | (unsigned)s.w;
                *(uint4*)(sh.p.vals + (g << 2)) = v;
                ushort4 bk;
                bk.x = (unsigned short)(d.x >> BSHIFT);
                bk.y = (unsigned short)(d.y >> BSHIFT);
                bk.z = (unsigned short)(d.z >> BSHIFT);
                bk.w = (unsigned short)(d.w >> BSHIFT);
                *(ushort4*)(sh.p.bkt + (g << 2)) = bk;
                atomicAdd(&sh.p.hist[bk.x], 1);
                atomicAdd(&sh.p.hist[bk.y], 1);
                atomicAdd(&sh.p.hist[bk.z], 1);
                atomicAdd(&sh.p.hist[bk.w], 1);
            }
            for (int i = (G << 2) + tid; i < m; i += 1024) {
                int d = edge_dst[e0 + i];
                int s = edge_src[e0 + i];
                int b = d >> BSHIFT;
                sh.p.vals[i] = ((unsigned)(d & (BN - 1)) << 20) | (unsigned)s;
                sh.p.bkt[i] = (unsigned short)b;
                atomicAdd(&sh.p.hist[b], 1);
            }
        }
        __syncthreads();

        // exclusive scan of hist over NB (Hillis-Steele, 10 rounds)
        if (tid < NB) sh.p.offs[tid] = sh.p.hist[tid];
        __syncthreads();
        for (int o = 1; o < NB; o <<= 1) {
            int t = 0;
            if (tid < NB && tid >= o) t = sh.p.offs[tid - o];
            __syncthreads();
            if (tid < NB) sh.p.offs[tid] += t;
            __syncthreads();
        }
        if (tid < NB) {
            int e = sh.p.offs[tid] - sh.p.hist[tid];   // exclusive
            sh.p.offs[tid] = e;
            sh.p.cur[tid] = e;
            blk_offs[pid * (NB + 1) + tid] = e;        // dense table write
        }
        if (tid == 0) blk_offs[pid * (NB + 1) + NB] = m;
        __syncthreads();

        // LDS counting-sort scatter (bucket-grouped)
        for (int i = tid; i < m; i += 1024) {
            int b = sh.p.bkt[i];
            int pos = atomicAdd(&sh.p.cur[b], 1);
            sh.p.srt[pos] = sh.p.vals[i];
        }
        __syncthreads();

        // fully coalesced sequential writeout of the sorted chunk
        unsigned* __restrict__ dst = bsorted + (size_t)pid * per4;
        for (int i = tid; i < m; i += 1024) dst[i] = sh.p.srt[i];
    } else {
        // ---------- transform: y = bf16(x @ W), MFMA, 16 waves ----------
        const int lane = tid & 63;
        const int w    = tid >> 6;            // 0..15
        const int l15  = lane & 15;
        const int l4   = lane >> 4;
        const int tb   = blockIdx.x >> 1;

        if (tb == 0 && tid < 8)   // zero row at index N_NODES
            ((uint4*)(y + (size_t)N_NODES * DIM))[tid] = make_uint4(0, 0, 0, 0);

        bf16x8 bfrag[4][2];
#pragma unroll
        for (int ct = 0; ct < 4; ++ct)
#pragma unroll
            for (int kt = 0; kt < 2; ++kt)
#pragma unroll
                for (int j = 0; j < 8; ++j) {
                    int k = kt * 32 + l4 * 8 + j;
                    int c = ct * 16 + l15;
                    bfrag[ct][kt][j] = (short)f2bf(W[k * DIM + c]);
                }

        ushort* myl = sh.t + w * (16 * 72);
        const int gw = tb * 16 + w;
        const int nw = NT * 16;

        for (int rt = gw; rt < N_TILES; rt += nw) {
            const float* xt = x + (size_t)rt * 16 * DIM;

            f32x4 zero = {0.f, 0.f, 0.f, 0.f};
            f32x4 acc0 = zero, acc1 = zero, acc2 = zero, acc3 = zero;
#pragma unroll
            for (int kt = 0; kt < 2; ++kt) {
                const float* ap = xt + (size_t)l15 * DIM + kt * 32 + l4 * 8;
                float4 p0 = *(const float4*)(ap);
                float4 p1 = *(const float4*)(ap + 4);
                bf16x8 afrag;
                afrag[0] = (short)f2bf(p0.x); afrag[1] = (short)f2bf(p0.y);
                afrag[2] = (short)f2bf(p0.z); afrag[3] = (short)f2bf(p0.w);
                afrag[4] = (short)f2bf(p1.x); afrag[5] = (short)f2bf(p1.y);
                afrag[6] = (short)f2bf(p1.z); afrag[7] = (short)f2bf(p1.w);
                acc0 = __builtin_amdgcn_mfma_f32_16x16x32_bf16(afrag, bfrag[0][kt], acc0, 0, 0, 0);
                acc1 = __builtin_amdgcn_mfma_f32_16x16x32_bf16(afrag, bfrag[1][kt], acc1, 0, 0, 0);
                acc2 = __builtin_amdgcn_mfma_f32_16x16x32_bf16(afrag, bfrag[2][kt], acc2, 0, 0, 0);
                acc3 = __builtin_amdgcn_mfma_f32_16x16x32_bf16(afrag, bfrag[3][kt], acc3, 0, 0, 0);
            }

#pragma unroll
            for (int r = 0; r < 4; ++r) {
                int mm = l4 * 4 + r;
                myl[mm * 72 +  0 + l15] = f2bf(acc0[r]);
                myl[mm * 72 + 16 + l15] = f2bf(acc1[r]);
                myl[mm * 72 + 32 + l15] = f2bf(acc2[r]);
                myl[mm * 72 + 48 + l15] = f2bf(acc3[r]);
            }
            int rr = lane >> 2, q = lane & 3;
            const uint4* src = (const uint4*)(myl + rr * 72 + q * 16);
            uint4 d0 = src[0];
            uint4 d1 = src[1];
            ushort* dst = y + ((size_t)(rt * 16 + rr)) * DIM + q * 16;
            *(uint4*)(dst)     = d0;
            *(uint4*)(dst + 8) = d1;
        }
    }
}

// ---- pass 2: assemble bucket from 256 runs + counting sort + gather ----
// 512 threads (8 waves) per bucket: doubles resident waves vs 256 to
// cover the random y-gather latency (R17: occupancy was only 25%).
__global__ __launch_bounds__(512)
void sort_gather_kernel(const ushort* __restrict__ y,
                        const int* __restrict__ blk_offs,
                        const unsigned* __restrict__ bsorted,
                        const float* __restrict__ bias,
                        float* __restrict__ out, int per4) {
    __shared__ unsigned vals[BC];      // 8 KB assembled entries
    __shared__ unsigned sorted[BC];    // 8 KB sorted src indices
    __shared__ int lens[NP];
    __shared__ int starts[NP];
    __shared__ int h[BN];
    __shared__ int tmp[BN];
    __shared__ int offs[BN + 1];
    __shared__ int cur[BN];
    __shared__ int cnt_sh;

    const int tid = threadIdx.x;     // 512 threads
    const int b = blockIdx.x;

    // stage A: per-block run table for this bucket + scan of lengths
    int lo = 0, len = 0;
    if (tid < NP) {
        const int* po = blk_offs + tid * (NB + 1);
        lo = po[b];
        len = po[b + 1] - lo;
        lens[tid] = len;
        starts[tid] = len;
    }
    __syncthreads();
    for (int o = 1; o < NP; o <<= 1) {
        int t = 0;
        if (tid < NP && tid >= o) t = starts[tid - o];
        __syncthreads();
        if (tid < NP) starts[tid] += t;
        __syncthreads();
    }
    if (tid == NP - 1) cnt_sh = starts[NP - 1];
    __syncthreads();
    int cnt = cnt_sh;
    if (cnt > BC) cnt = BC;

    // stage B: copy runs into vals (one run per thread, L2-resident reads)
    if (tid < NP) {
        int st = starts[tid] - len;    // exclusive prefix
        const unsigned* __restrict__ src = bsorted + (size_t)tid * per4 + lo;
        for (int j = 0; j < len; ++j) {
            int p = st + j;
            if (p < BC) vals[p] = src[j];
        }
    }

    // stage C: counting sort by local node id
    for (int i = tid; i < BN; i += 512) h[i] = 0;
    __syncthreads();
    for (int i = tid; i < cnt; i += 512) atomicAdd(&h[vals[i] >> 20], 1);
    __syncthreads();

    if (tid < BN) tmp[tid] = h[tid];
    __syncthreads();
    for (int o = 1; o < BN; o <<= 1) {
        int t = 0;
        if (tid < BN && tid >= o) t = tmp[tid - o];
        __syncthreads();
        if (tid < BN) tmp[tid] += t;
        __syncthreads();
    }
    if (tid < BN) {
        int e = tmp[tid] - h[tid];
        offs[tid] = e;
        cur[tid] = e;
    }
    if (tid == 0) offs[BN] = cnt;
    __syncthreads();

    for (int i = tid; i < cnt; i += 512) {
        unsigned v = vals[i];
        int pos = atomicAdd(&cur[v >> 20], 1);
        sorted[pos] = v & 0xFFFFFu;
    }
    __syncthreads();

    // stage D: register-accumulated gather + bias + coalesced store
    const int grp = tid >> 4;        // 32 groups of 16 lanes
    const int f = tid & 15;
    const uint2* __restrict__ y2 = (const uint2*)y;
    const int node0 = b * BN;
    float4 bb = ((const float4*)bias)[f];

    for (int r = grp; r < BN; r += 32) {
        int nd = node0 + r;
        if (nd >= N_NODES) break;
        int s0i = offs[r], e0i = offs[r + 1];
        float a0 = 0.f, a1 = 0.f, a2 = 0.f, a3 = 0.f;
        for (int i = s0i; i < e0i; i += 8) {
            int idx[8];
#pragma unroll
            for (int k = 0; k < 8; ++k)
                idx[k] = (i + k < e0i) ? (int)sorted[i + k] : N_NODES;
#pragma unroll
            for (int k = 0; k < 8; ++k) {
                uint2 v = y2[(size_t)idx[k] * 16 + f];
                a0 += __uint_as_float(v.x << 16);
                a1 += __uint_as_float(v.x & 0xffff0000u);
                a2 += __uint_as_float(v.y << 16);
                a3 += __uint_as_float(v.y & 0xffff0000u);
            }
        }
        float4 o;
        o.x = a0 + bb.x; o.y = a1 + bb.y; o.z = a2 + bb.z; o.w = a3 + bb.w;
        *(float4*)(out + (size_t)nd * DIM + f * 4) = o;
    }
}

// ---- Launch ------------------------------------------------------------

extern "C" void kernel_launch(void* const* d_in, const int* in_sizes, int n_in,
                              void* d_out, int out_size, void* d_ws, size_t ws_size,
                              hipStream_t stream) {
    const float* x        = (const float*)d_in[0];
    const int*   edge_src = (const int*)d_in[1];
    const int*   edge_dst = (const int*)d_in[2];
    const float* W        = (const float*)d_in[3];
    const float* b        = (const float*)d_in[4];
    float* out = (float*)d_out;

    const int E = in_sizes[1];
    int per4 = (((E + NP - 1) / NP) + 3) & ~3;   // 4884 for E=1.25M
    if (per4 > CHUNK_P) per4 = CHUNK_P;          // safety (not hit here)

    // ws layout: y[(N+1)*64] bf16 (12.8 MB) | bsorted[NP*CHUNK_P] (5.05 MB)
    //            | blk_offs[NP*(NB+1)] (0.80 MB)   -- no memset needed
    ushort*   y        = (ushort*)d_ws;
    unsigned* bsorted  = (unsigned*)(y + (size_t)(N_NODES + 1) * DIM);
    int*      blk_offs = (int*)(bsorted + (size_t)NP * CHUNK_P);

    prep_kernel<<<NP + NT, 1024, 0, stream>>>(x, W, edge_src, edge_dst,
                                              blk_offs, bsorted, y, E, per4);
    sort_gather_kernel<<<NB, 512, 0, stream>>>(y, blk_offs, bsorted, b, out,
                                               per4);
}